// Round 2
// baseline (694.635 us; speedup 1.0000x reference)
//
#include <hip/hip_runtime.h>
#include <hip/hip_bf16.h>

typedef _Float16 f16x8 __attribute__((ext_vector_type(8)));
typedef _Float16 f16x4 __attribute__((ext_vector_type(4)));
typedef float f32x4 __attribute__((ext_vector_type(4)));

__device__ __forceinline__ float tanh_fast(float x) {
  float e = __expf(2.0f * x);
  return 1.0f - 2.0f * __builtin_amdgcn_rcpf(e + 1.0f);
}
__device__ __forceinline__ float sigmoid_fast(float x) {
  return __builtin_amdgcn_rcpf(1.0f + __expf(-x));
}

// ---------------- K0: weight prep (unchanged) ----------------
// Fragment tiles of 512 hw. PI k-order (W2, Wq1): lane l elem j holds
// B[k = kt*32 + pi(q,j)][col = nt*16 + l15], pi(q,j) = q*4 + (j&3) + 16*(j>>2).
// Plain k-order (Wq2, W1): k = q*8 + j.
// V2p tile = kt*64 + nt; T1p tile = kt*16 + nt; T2p tile = nt*8 + kt.
__global__ __launch_bounds__(256) void prep_weights(
    const float* __restrict__ W1, const float* __restrict__ W2,
    const float* __restrict__ Wq1, const float* __restrict__ Wq2,
    _Float16* __restrict__ V1p, _Float16* __restrict__ V2p,
    _Float16* __restrict__ T1p, _Float16* __restrict__ T2p) {
  __shared__ float S[32 * 33];
  int b = blockIdx.x, t = threadIdx.x;
  if (b < 2624) {
    const float* in; _Float16* out; int N, nc0, tile, use_pi;
    if (b < 2048) {        // W2 [32][1024][32]: h, ntl, kt  (PI)
      int h = b >> 6, rem = b & 63, ntl = rem >> 5, kt = rem & 31;
      in = W2 + (size_t)h * 32768 + (size_t)kt * 32 * 32;
      N = 32; nc0 = ntl * 16;
      out = V2p; tile = kt * 64 + (h * 2 + ntl); use_pi = 1;
    } else if (b < 2560) { // Wq1 [1024][256]  (PI)
      int i = b - 2048, nt = i >> 5, kt = i & 31;
      in = Wq1 + (size_t)kt * 32 * 256; N = 256; nc0 = nt * 16;
      out = T1p; tile = kt * 16 + nt; use_pi = 1;
    } else {               // Wq2 [256][128]  (plain)
      int i = b - 2560, nt = i >> 3, kt = i & 7;
      in = Wq2 + (size_t)kt * 32 * 128; N = 128; nc0 = nt * 16;
      out = T2p; tile = nt * 8 + kt; use_pi = 0;
    }
    if (t < 128) {
      int r = t >> 2, c4 = (t & 3) * 4;
      const float4 v = *(const float4*)(in + (size_t)r * N + nc0 + c4);
      S[r * 17 + c4 + 0] = v.x; S[r * 17 + c4 + 1] = v.y;
      S[r * 17 + c4 + 2] = v.z; S[r * 17 + c4 + 3] = v.w;
    }
    __syncthreads();
    if (t < 128) {
      int w2 = t >> 6, l = t & 63, q = l >> 4, l15 = l & 15;
      f16x4 o;
#pragma unroll
      for (int jj = 0; jj < 4; ++jj) {
        int kl = use_pi ? (q * 4 + jj + w2 * 16) : (q * 8 + w2 * 4 + jj);
        o[jj] = (_Float16)S[kl * 17 + l15];
      }
      *(f16x4*)(out + (size_t)tile * 512 + l * 8 + w2 * 4) = o;
    }
  } else {                 // W1 [32][32][32]: one block per head h (plain)
    int h = b - 2624;
    const float* in = W1 + h * 1024;
    int cc = t & 31, rr8 = t >> 5;
#pragma unroll
    for (int p = 0; p < 4; ++p) {
      int r = rr8 + p * 8;
      S[cc * 33 + r] = in[r * 32 + cc];
    }
    __syncthreads();
    if (t < 128) {
      int ntl = t >> 6, l = t & 63, q = l >> 4, l15 = l & 15;
      f16x8 o;
#pragma unroll
      for (int j = 0; j < 8; ++j)
        o[j] = (_Float16)S[(ntl * 16 + l15) * 33 + q * 8 + j];
      *(f16x8*)(V1p + (size_t)(h * 2 + ntl) * 512 + l * 8) = o;
    }
  }
}

// ---------------- K1: ripple1 producer ----------------
// One block = 64 rows, 256 threads (4 waves). Wave w computes head range
// ktL = w*8..w*8+7 for its block's 4 row-tiles. Writes x1 fragments in PI
// k-order (identical layout Rphase used to write into XF):
//   frag index = ktL*NRT + rt, lane l elem j = x1[rt*16 + l15][ktL*32 + pi(q,j)]
// Each x1 element computed exactly ONCE (old fused kernel recomputed 4x).
__global__ __launch_bounds__(256) void k1_ripple1(
    const float* __restrict__ state, const float* __restrict__ action,
    const _Float16* __restrict__ v1p, const float* __restrict__ b1,
    const float* __restrict__ g1, _Float16* __restrict__ x1p,
    int gro, int NRT) {
  __shared__ __align__(16) _Float16 SA[64 * 40];
  int bm = blockIdx.x;
  int t = threadIdx.x, w = t >> 6, l = t & 63, q = l >> 4, l15 = l & 15;
  {  // stage sa tile [64][32] fp16, stride 40; 4 threads/row (8 floats each)
    int r = t >> 2, qq = t & 3;
    size_t grow = (size_t)(gro + bm * 64 + r);
    const float* src = (qq < 3) ? (state + grow * 24 + qq * 8)
                                : (action + grow * 8);
    float4 v0 = ((const float4*)src)[0];
    float4 v1 = ((const float4*)src)[1];
    float v[8] = {v0.x, v0.y, v0.z, v0.w, v1.x, v1.y, v1.z, v1.w};
    f16x8 h;
#pragma unroll
    for (int j = 0; j < 8; ++j) h[j] = (_Float16)v[j];
    *(f16x8*)&SA[r * 40 + qq * 8] = h;
  }
  __syncthreads();

  f16x8 asa[4];
#pragma unroll
  for (int p = 0; p < 4; ++p)
    asa[p] = *(const f16x8*)&SA[(p * 16 + l15) * 40 + q * 8];

#pragma unroll
  for (int i = 0; i < 8; ++i) {
    int ktL = w * 8 + i;  // head index (32 x1-cols per head)
    f16x8 rb0 = *(const f16x8*)(v1p + (size_t)(2 * ktL) * 512 + l * 8);
    f16x8 rb1 = *(const f16x8*)(v1p + (size_t)(2 * ktL + 1) * 512 + l * 8);
    float sg = sigmoid_fast(g1[ktL]);
    f32x4 bs0 = *(const f32x4*)(b1 + ktL * 32 + q * 4);
    f32x4 bs1 = *(const f32x4*)(b1 + ktL * 32 + 16 + q * 4);
    _Float16* op = x1p + ((size_t)ktL * NRT + bm * 4) * 512 + l * 8;
#pragma unroll
    for (int p = 0; p < 4; ++p) {
      f32x4 d0 = {}, d1 = {};
      d0 = __builtin_amdgcn_mfma_f32_16x16x32_f16(rb0, asa[p], d0, 0, 0, 0);
      d1 = __builtin_amdgcn_mfma_f32_16x16x32_f16(rb1, asa[p], d1, 0, 0, 0);
      f16x8 o;
#pragma unroll
      for (int r = 0; r < 4; ++r) {
        o[r]     = (_Float16)(tanh_fast(d0[r] + bs0[r]) * sg);
        o[4 + r] = (_Float16)(tanh_fast(d1[r] + bs1[r]) * sg);
      }
      *(f16x8*)(op + (size_t)p * 512) = o;
    }
  }
}

// ---------------- K2: ripple2 barrier-free streaming GEMM ----------------
// Block = 128 rows x 512 cols, 512 threads (8 waves = 2 wrow x 4 wcol),
// wave = 64 rows x 128 cols, acc[4][8] (same per-wave shape as before).
// NO LDS, NO barriers: A-frags stream from x1p (3-deep prefetch covers L3
// latency), B ping-pongs from L2-resident v2p. A re-read = 2x (was 4x).
__global__ __launch_bounds__(512, 2) void k2_ripple2(
    const _Float16* __restrict__ x1p, const _Float16* __restrict__ v2p,
    const float* __restrict__ b2, const float* __restrict__ g2,
    _Float16* __restrict__ x2p, int NRT) {
  int g = blockIdx.x;
  int bn = g & 1, bm = g >> 1;
  int t = threadIdx.x, w = t >> 6, l = t & 63, q = l >> 4, l15 = l & 15;
  int wrow = w >> 2, wcol = w & 3;
  const int nt0 = bn * 32 + wcol * 8;
  const _Float16* bBase = v2p + (size_t)nt0 * 512 + (size_t)l * 8;
  const _Float16* aBase = x1p + (size_t)(bm * 8 + wrow * 4) * 512 + (size_t)l * 8;
  const size_t aK = (size_t)NRT * 512;

  f32x4 acc[4][8] = {};
  f16x8 bb0[4], bb1[4];
  f16x8 xa[3][4];  // statically indexed (kt fully unrolled) -> stays in VGPRs

#pragma unroll
  for (int mi = 0; mi < 4; ++mi) xa[0][mi] = *(const f16x8*)(aBase + mi * 512);
#pragma unroll
  for (int mi = 0; mi < 4; ++mi) xa[1][mi] = *(const f16x8*)(aBase + aK + mi * 512);
#pragma unroll
  for (int n2 = 0; n2 < 4; ++n2) bb0[n2] = *(const f16x8*)(bBase + (size_t)n2 * 512);
#pragma unroll
  for (int n2 = 0; n2 < 4; ++n2) bb1[n2] = *(const f16x8*)(bBase + (size_t)(4 + n2) * 512);

#pragma unroll
  for (int kt = 0; kt < 32; ++kt) {
    // A prefetch 2 kt ahead (slot (kt+2)%3 == (kt-1)%3, already consumed)
    if (kt < 30) {
#pragma unroll
      for (int mi = 0; mi < 4; ++mi)
        xa[(kt + 2) % 3][mi] =
            *(const f16x8*)(aBase + (size_t)(kt + 2) * aK + mi * 512);
    }
    // half 0 (ni 0..3)
#pragma unroll
    for (int mi = 0; mi < 4; ++mi)
#pragma unroll
      for (int n2 = 0; n2 < 4; ++n2)
        acc[mi][n2] = __builtin_amdgcn_mfma_f32_16x16x32_f16(
            bb0[n2], xa[kt % 3][mi], acc[mi][n2], 0, 0, 0);
    if (kt < 31) {
#pragma unroll
      for (int n2 = 0; n2 < 4; ++n2)
        bb0[n2] = *(const f16x8*)(bBase + (size_t)((kt + 1) * 64 + n2) * 512);
    }
    // half 1 (ni 4..7)
#pragma unroll
    for (int mi = 0; mi < 4; ++mi)
#pragma unroll
      for (int n2 = 0; n2 < 4; ++n2)
        acc[mi][4 + n2] = __builtin_amdgcn_mfma_f32_16x16x32_f16(
            bb1[n2], xa[kt % 3][mi], acc[mi][4 + n2], 0, 0, 0);
    if (kt < 31) {
#pragma unroll
      for (int n2 = 0; n2 < 4; ++n2)
        bb1[n2] = *(const f16x8*)(bBase + (size_t)((kt + 1) * 64 + 4 + n2) * 512);
    }
  }

  // epilogue: tanh+gate in registers -> direct fragment-major x2p stores
#pragma unroll
  for (int mi = 0; mi < 4; ++mi) {
    int rt = bm * 8 + wrow * 4 + mi;
#pragma unroll
    for (int p2 = 0; p2 < 4; ++p2) {
      int kc2 = (nt0 >> 1) + p2;
      float sg2 = sigmoid_fast(g2[kc2]);
      f32x4 c0 = *(const f32x4*)(b2 + kc2 * 32 + q * 4);
      f32x4 c1 = *(const f32x4*)(b2 + kc2 * 32 + 16 + q * 4);
      f16x8 o;
#pragma unroll
      for (int r = 0; r < 4; ++r) {
        o[r]     = (_Float16)(tanh_fast(acc[mi][2 * p2][r] + c0[r]) * sg2);
        o[4 + r] = (_Float16)(tanh_fast(acc[mi][2 * p2 + 1][r] + c1[r]) * sg2);
      }
      *(f16x8*)(x2p + ((size_t)kc2 * NRT + rt) * 512 + l * 8) = o;
    }
  }
}

// ---------------- K3: fused q-network head (unchanged) ----------------
__global__ __launch_bounds__(512, 3) void k3_head(
    const _Float16* __restrict__ x2p, const _Float16* __restrict__ t1p,
    const _Float16* __restrict__ t2p,
    const float* __restrict__ bq1, const float* __restrict__ ln1g, const float* __restrict__ ln1b,
    const float* __restrict__ bq2, const float* __restrict__ ln2g, const float* __restrict__ ln2b,
    const float* __restrict__ wq3, const float* __restrict__ bq3,
    float* __restrict__ out, int NRT, int SROWS) {
  __shared__ __align__(16) _Float16 y1h[128 * 264];
  __shared__ float redA[128 * 4], redB[128 * 4];
  __shared__ float meanv[128], rstdv[128];
  int bm = blockIdx.x;
  int t = threadIdx.x, w = t >> 6, l = t & 63, q = l >> 4, l15 = l & 15;
  int wr = w >> 2, wc = w & 3;

  int gt = bm * 8;
  int slice = 0;
  if (gt >= NRT) { slice = 1; gt -= NRT; }
  int rt0 = gt + wr * 4;

  f32x4 acc[4][4] = {};
  const size_t aStep = (size_t)NRT * 512;
  const _Float16* aP = x2p + (size_t)slice * SROWS * 1024 + (size_t)rt0 * 512 + (size_t)l * 8;
  const _Float16* bP = t1p + (size_t)(wc * 4) * 512 + (size_t)l * 8;

  f16x8 a0[4], a1[4], b0[4], b1[4];
#pragma unroll
  for (int mi = 0; mi < 4; ++mi) a0[mi] = *(const f16x8*)(aP + mi * 512);
#pragma unroll
  for (int ni = 0; ni < 4; ++ni) b0[ni] = *(const f16x8*)(bP + ni * 512);
#pragma unroll
  for (int mi = 0; mi < 4; ++mi) a1[mi] = *(const f16x8*)(aP + aStep + mi * 512);
#pragma unroll
  for (int ni = 0; ni < 4; ++ni) b1[ni] = *(const f16x8*)(bP + 8192 + ni * 512);
  aP += 2 * aStep; bP += 16384;

  for (int kt = 0; kt < 32; kt += 2) {
#pragma unroll
    for (int mi = 0; mi < 4; ++mi)
#pragma unroll
      for (int ni = 0; ni < 4; ++ni)
        acc[mi][ni] = __builtin_amdgcn_mfma_f32_16x16x32_f16(a0[mi], b0[ni], acc[mi][ni], 0, 0, 0);
    if (kt < 30) {
#pragma unroll
      for (int mi = 0; mi < 4; ++mi) a0[mi] = *(const f16x8*)(aP + mi * 512);
#pragma unroll
      for (int ni = 0; ni < 4; ++ni) b0[ni] = *(const f16x8*)(bP + ni * 512);
    }
#pragma unroll
    for (int mi = 0; mi < 4; ++mi)
#pragma unroll
      for (int ni = 0; ni < 4; ++ni)
        acc[mi][ni] = __builtin_amdgcn_mfma_f32_16x16x32_f16(a1[mi], b1[ni], acc[mi][ni], 0, 0, 0);
    if (kt < 30) {
#pragma unroll
      for (int mi = 0; mi < 4; ++mi) a1[mi] = *(const f16x8*)(aP + aStep + mi * 512);
#pragma unroll
      for (int ni = 0; ni < 4; ++ni) b1[ni] = *(const f16x8*)(bP + 8192 + ni * 512);
      aP += 2 * aStep; bP += 16384;
    }
  }

#pragma unroll
  for (int ni = 0; ni < 4; ++ni) {
    int col = wc * 64 + ni * 16 + l15;
    float b = bq1[col];
#pragma unroll
    for (int mi = 0; mi < 4; ++mi)
#pragma unroll
      for (int r = 0; r < 4; ++r) acc[mi][ni][r] += b;
  }
#pragma unroll
  for (int mi = 0; mi < 4; ++mi)
#pragma unroll
    for (int r = 0; r < 4; ++r) {
      int row = wr * 64 + mi * 16 + q * 4 + r;
      float s = 0.f, sq = 0.f;
#pragma unroll
      for (int ni = 0; ni < 4; ++ni) { float v = acc[mi][ni][r]; s += v; sq += v * v; }
#pragma unroll
      for (int off = 1; off < 16; off <<= 1) { s += __shfl_xor(s, off); sq += __shfl_xor(sq, off); }
      if (l15 == 0) { redA[row * 4 + wc] = s; redB[row * 4 + wc] = sq; }
    }
  __syncthreads();
  if (t < 128) {
    float s  = redA[t * 4] + redA[t * 4 + 1] + redA[t * 4 + 2] + redA[t * 4 + 3];
    float sq = redB[t * 4] + redB[t * 4 + 1] + redB[t * 4 + 2] + redB[t * 4 + 3];
    float mean = s * (1.0f / 256.0f);
    float var = sq * (1.0f / 256.0f) - mean * mean;
    meanv[t] = mean; rstdv[t] = rsqrtf(var + 1e-5f);
  }
  __syncthreads();
#pragma unroll
  for (int mi = 0; mi < 4; ++mi)
#pragma unroll
    for (int ni = 0; ni < 4; ++ni)
#pragma unroll
      for (int r = 0; r < 4; ++r) {
        int row = wr * 64 + mi * 16 + q * 4 + r;
        int col = wc * 64 + ni * 16 + l15;
        float y = (acc[mi][ni][r] - meanv[row]) * rstdv[row] * ln1g[col] + ln1b[col];
        y = fmaxf(y, 0.f);
        y1h[row * 264 + col] = (_Float16)y;
      }
  __syncthreads();

  f32x4 a2[4][2] = {};
  for (int kt = 0; kt < 8; ++kt) {
    f16x8 af2[4];
#pragma unroll
    for (int mi = 0; mi < 4; ++mi)
      af2[mi] = *(const f16x8*)&y1h[(wr * 64 + mi * 16 + l15) * 264 + kt * 32 + q * 8];
#pragma unroll
    for (int ni = 0; ni < 2; ++ni) {
      f16x8 bf = *(const f16x8*)(t2p + (size_t)(wc * 2 + ni) * 4096 + kt * 512 + l * 8);
#pragma unroll
      for (int mi = 0; mi < 4; ++mi)
        a2[mi][ni] = __builtin_amdgcn_mfma_f32_16x16x32_f16(af2[mi], bf, a2[mi][ni], 0, 0, 0);
    }
  }
#pragma unroll
  for (int ni = 0; ni < 2; ++ni) {
    int col = wc * 32 + ni * 16 + l15;
    float b = bq2[col];
#pragma unroll
    for (int mi = 0; mi < 4; ++mi)
#pragma unroll
      for (int r = 0; r < 4; ++r) a2[mi][ni][r] += b;
  }
  __syncthreads();
#pragma unroll
  for (int mi = 0; mi < 4; ++mi)
#pragma unroll
    for (int r = 0; r < 4; ++r) {
      int row = wr * 64 + mi * 16 + q * 4 + r;
      float s = 0.f, sq = 0.f;
#pragma unroll
      for (int ni = 0; ni < 2; ++ni) { float v = a2[mi][ni][r]; s += v; sq += v * v; }
#pragma unroll
      for (int off = 1; off < 16; off <<= 1) { s += __shfl_xor(s, off); sq += __shfl_xor(sq, off); }
      if (l15 == 0) { redA[row * 4 + wc] = s; redB[row * 4 + wc] = sq; }
    }
  __syncthreads();
  if (t < 128) {
    float s  = redA[t * 4] + redA[t * 4 + 1] + redA[t * 4 + 2] + redA[t * 4 + 3];
    float sq = redB[t * 4] + redB[t * 4 + 1] + redB[t * 4 + 2] + redB[t * 4 + 3];
    float mean = s * (1.0f / 128.0f);
    float var = sq * (1.0f / 128.0f) - mean * mean;
    meanv[t] = mean; rstdv[t] = rsqrtf(var + 1e-5f);
  }
  __syncthreads();
#pragma unroll
  for (int mi = 0; mi < 4; ++mi)
#pragma unroll
    for (int r = 0; r < 4; ++r) {
      int row = wr * 64 + mi * 16 + q * 4 + r;
      float pr = 0.f;
#pragma unroll
      for (int ni = 0; ni < 2; ++ni) {
        int col = wc * 32 + ni * 16 + l15;
        float y = (a2[mi][ni][r] - meanv[row]) * rstdv[row] * ln2g[col] + ln2b[col];
        y = fmaxf(y, 0.f);
        pr += y * wq3[col];
      }
#pragma unroll
      for (int off = 1; off < 16; off <<= 1) pr += __shfl_xor(pr, off);
      if (l15 == 0) redA[row * 4 + wc] = pr;
    }
  __syncthreads();
  if (t < 128)
    out[bm * 128 + t] = redA[t * 4] + redA[t * 4 + 1] + redA[t * 4 + 2] + redA[t * 4 + 3] + bq3[0];
}

// ---------------- launcher ----------------
extern "C" void kernel_launch(void* const* d_in, const int* in_sizes, int n_in,
                              void* d_out, int out_size, void* d_ws, size_t ws_size,
                              hipStream_t stream) {
  const float* state  = (const float*)d_in[0];
  const float* action = (const float*)d_in[1];
  const float* W1  = (const float*)d_in[2];
  const float* b1  = (const float*)d_in[3];
  const float* g1  = (const float*)d_in[4];
  const float* W2  = (const float*)d_in[5];
  const float* b2  = (const float*)d_in[6];
  const float* g2  = (const float*)d_in[7];
  const float* Wq1 = (const float*)d_in[8];
  const float* bq1 = (const float*)d_in[9];
  const float* ln1g = (const float*)d_in[10];
  const float* ln1b = (const float*)d_in[11];
  const float* Wq2 = (const float*)d_in[12];
  const float* bq2 = (const float*)d_in[13];
  const float* ln2g = (const float*)d_in[14];
  const float* ln2b = (const float*)d_in[15];
  const float* Wq3 = (const float*)d_in[16];
  const float* bq3 = (const float*)d_in[17];
  int B = in_sizes[0] / 24;

  char* ws = (char*)d_ws;
  _Float16* V1p = (_Float16*)(ws);
  _Float16* V2p = (_Float16*)(ws + 65536);
  _Float16* T1p = (_Float16*)(ws + 65536 + 2097152);
  _Float16* T2p = (_Float16*)(ws + 65536 + 2097152 + 524288);
  size_t woff = (65536 + 2097152 + 524288 + 65536 + 4095) & ~(size_t)4095;

  size_t avail = ws_size > woff ? ws_size - woff : 0;
  long rows = (long)(avail / 4096);     // per row: x2 fp16 (2048 B) + x1 fp16 (2048 B)
  if (rows > 32768) rows = 32768;
  rows &= ~127L;
  if (rows < 128) rows = 128;
  int S = (int)rows;
  _Float16* x2 = (_Float16*)(ws + woff);
  _Float16* x1 = (_Float16*)(ws + woff + (size_t)S * 2048);
  int NRT = S / 16;

  prep_weights<<<2656, 256, 0, stream>>>(W1, W2, Wq1, Wq2, V1p, V2p, T1p, T2p);

  for (int r0 = 0; r0 < B; r0 += S) {
    int Sc = S < (B - r0) ? S : (B - r0);
    int nbm = Sc / 128;
    k1_ripple1<<<dim3(Sc / 64), 256, 0, stream>>>(state, action, V1p, b1, g1,
                                                  x1, r0, NRT);
    k2_ripple2<<<dim3(2 * nbm), 512, 0, stream>>>(x1, V2p, b2, g2, x2, NRT);
    k3_head<<<dim3(nbm), 512, 0, stream>>>(x2, T1p, T2p, bq1, ln1g, ln1b,
                                           bq2, ln2g, ln2b, Wq3, bq3,
                                           (float*)d_out + r0, NRT, S);
  }
}

// Round 3
// 641.321 us; speedup vs baseline: 1.0831x; 1.0831x over previous
//
#include <hip/hip_runtime.h>
#include <hip/hip_bf16.h>

typedef _Float16 f16x8 __attribute__((ext_vector_type(8)));
typedef _Float16 f16x4 __attribute__((ext_vector_type(4)));
typedef float f32x4 __attribute__((ext_vector_type(4)));

__device__ __forceinline__ float tanh_fast(float x) {
  float e = __expf(2.0f * x);
  return 1.0f - 2.0f * __builtin_amdgcn_rcpf(e + 1.0f);
}
__device__ __forceinline__ float sigmoid_fast(float x) {
  return __builtin_amdgcn_rcpf(1.0f + __expf(-x));
}

// ---------------- K0: weight prep (unchanged) ----------------
// Fragment tiles of 512 hw. PI k-order (W2, Wq1): lane l elem j holds
// B[k = kt*32 + pi(q,j)][col = nt*16 + l15], pi(q,j) = q*4 + (j&3) + 16*(j>>2).
// Plain k-order (Wq2, W1): k = q*8 + j.
// V2p tile = kt*64 + nt; T1p tile = kt*16 + nt; T2p tile = nt*8 + kt.
__global__ __launch_bounds__(256) void prep_weights(
    const float* __restrict__ W1, const float* __restrict__ W2,
    const float* __restrict__ Wq1, const float* __restrict__ Wq2,
    _Float16* __restrict__ V1p, _Float16* __restrict__ V2p,
    _Float16* __restrict__ T1p, _Float16* __restrict__ T2p) {
  __shared__ float S[32 * 33];
  int b = blockIdx.x, t = threadIdx.x;
  if (b < 2624) {
    const float* in; _Float16* out; int N, nc0, tile, use_pi;
    if (b < 2048) {        // W2 [32][1024][32]: h, ntl, kt  (PI)
      int h = b >> 6, rem = b & 63, ntl = rem >> 5, kt = rem & 31;
      in = W2 + (size_t)h * 32768 + (size_t)kt * 32 * 32;
      N = 32; nc0 = ntl * 16;
      out = V2p; tile = kt * 64 + (h * 2 + ntl); use_pi = 1;
    } else if (b < 2560) { // Wq1 [1024][256]  (PI)
      int i = b - 2048, nt = i >> 5, kt = i & 31;
      in = Wq1 + (size_t)kt * 32 * 256; N = 256; nc0 = nt * 16;
      out = T1p; tile = kt * 16 + nt; use_pi = 1;
    } else {               // Wq2 [256][128]  (plain)
      int i = b - 2560, nt = i >> 3, kt = i & 7;
      in = Wq2 + (size_t)kt * 32 * 128; N = 128; nc0 = nt * 16;
      out = T2p; tile = nt * 8 + kt; use_pi = 0;
    }
    if (t < 128) {
      int r = t >> 2, c4 = (t & 3) * 4;
      const float4 v = *(const float4*)(in + (size_t)r * N + nc0 + c4);
      S[r * 17 + c4 + 0] = v.x; S[r * 17 + c4 + 1] = v.y;
      S[r * 17 + c4 + 2] = v.z; S[r * 17 + c4 + 3] = v.w;
    }
    __syncthreads();
    if (t < 128) {
      int w2 = t >> 6, l = t & 63, q = l >> 4, l15 = l & 15;
      f16x4 o;
#pragma unroll
      for (int jj = 0; jj < 4; ++jj) {
        int kl = use_pi ? (q * 4 + jj + w2 * 16) : (q * 8 + w2 * 4 + jj);
        o[jj] = (_Float16)S[kl * 17 + l15];
      }
      *(f16x4*)(out + (size_t)tile * 512 + l * 8 + w2 * 4) = o;
    }
  } else {                 // W1 [32][32][32]: one block per head h (plain)
    int h = b - 2624;
    const float* in = W1 + h * 1024;
    int cc = t & 31, rr8 = t >> 5;
#pragma unroll
    for (int p = 0; p < 4; ++p) {
      int r = rr8 + p * 8;
      S[cc * 33 + r] = in[r * 32 + cc];
    }
    __syncthreads();
    if (t < 128) {
      int ntl = t >> 6, l = t & 63, q = l >> 4, l15 = l & 15;
      f16x8 o;
#pragma unroll
      for (int j = 0; j < 8; ++j)
        o[j] = (_Float16)S[(ntl * 16 + l15) * 33 + q * 8 + j];
      *(f16x8*)(V1p + (size_t)(h * 2 + ntl) * 512 + l * 8) = o;
    }
  }
}

// ---------------- K12: fused ripple1+ripple2, 64x512 blocks ----------------
// Block = 64 rows x 512 cols, 256 threads = 4 waves; wave = 64 rows x 128
// cols (wcol = w). Ripple1 redundancy is 2x (was 4x at 256-col blocks):
// per wave per kc, Rphase computes ONE head (8 MFMA + 32 tanh) instead of
// two. Per-wave consumer structure (acc[4][8], bb ping-pong, XF dbuf
// exchange, R at j==2) identical to the verified 256-col kernel.
// LDS = 5 KB SA + 32 KB XF = 37 KB; 2 blocks/CU co-resident (reg-capped at
// 2 waves/SIMD) for cross-block overlap of barrier/R stalls.
__global__ __launch_bounds__(256, 2) void k12_fused(
    const float* __restrict__ state, const float* __restrict__ action,
    const _Float16* __restrict__ v1p, const float* __restrict__ b1,
    const float* __restrict__ g1,
    const _Float16* __restrict__ v2p, const float* __restrict__ b2,
    const float* __restrict__ g2,
    _Float16* __restrict__ x2p, int gro, int NRT) {
  __shared__ __align__(16) _Float16 SA[64 * 40];         // 5 KB
  __shared__ __align__(16) _Float16 XF[2 * 8192];        // 32 KB frag dbuf
  int g = blockIdx.x;
  int bn = g & 1, bm = g >> 1;
  int t = threadIdx.x, w = t >> 6, l = t & 63, q = l >> 4, l15 = l & 15;
  int wcol = w;
  int m0 = bm * 64;

  {  // stage sa tile [64][32] fp16, stride 40; 4 threads/row (8 floats each)
    int r = t >> 2, qq = t & 3;
    size_t grow = (size_t)(gro + m0 + r);
    const float* src = (qq < 3) ? (state + grow * 24 + qq * 8)
                                : (action + grow * 8);
    float4 v0 = ((const float4*)src)[0];
    float4 v1 = ((const float4*)src)[1];
    float v[8] = {v0.x, v0.y, v0.z, v0.w, v1.x, v1.y, v1.z, v1.w};
    f16x8 h;
#pragma unroll
    for (int j = 0; j < 8; ++j) h[j] = (_Float16)v[j];
    *(f16x8*)&SA[r * 40 + qq * 8] = h;
  }
  __syncthreads();

  // loop-invariant sa fragments (B operand of R phase), all 64 block rows
  f16x8 asa[4];
#pragma unroll
  for (int p = 0; p < 4; ++p)
    asa[p] = *(const f16x8*)&SA[(p * 16 + l15) * 40 + q * 8];

  const int nt0 = bn * 32 + wcol * 8;
  const _Float16* bBase = v2p + (size_t)nt0 * 512 + (size_t)l * 8;
  f32x4 acc[4][8] = {};

  // R phase: wave produces x1 rows 0..63, head ktL = kcn*4 + wcol
  // (32 k-cols), into XF tiles (wcol*4 + p).
  auto Rphase = [&](int kcn) {
    int ktL = kcn * 4 + wcol;
    f16x8 rb0 = *(const f16x8*)(v1p + (size_t)(2 * ktL) * 512 + l * 8);
    f16x8 rb1 = *(const f16x8*)(v1p + (size_t)(2 * ktL + 1) * 512 + l * 8);
    float sg = sigmoid_fast(g1[ktL]);
    f32x4 bs0 = *(const f32x4*)(b1 + ktL * 32 + q * 4);
    f32x4 bs1 = *(const f32x4*)(b1 + ktL * 32 + 16 + q * 4);
    _Float16* bw = XF + ((kcn & 1) * 8192);
#pragma unroll
    for (int p = 0; p < 4; ++p) {
      f32x4 d0 = {}, d1 = {};
      d0 = __builtin_amdgcn_mfma_f32_16x16x32_f16(rb0, asa[p], d0, 0, 0, 0);
      d1 = __builtin_amdgcn_mfma_f32_16x16x32_f16(rb1, asa[p], d1, 0, 0, 0);
      f16x8 o;
#pragma unroll
      for (int r = 0; r < 4; ++r) {
        o[r]     = (_Float16)(tanh_fast(d0[r] + bs0[r]) * sg);
        o[4 + r] = (_Float16)(tanh_fast(d1[r] + bs1[r]) * sg);
      }
      *(f16x8*)(bw + (size_t)(wcol * 4 + p) * 512 + l * 8) = o;
    }
  };

  // prologue: B stream kt=0 halves + R(0)
  f16x8 bb0[4], bb1v[4];
#pragma unroll
  for (int n2 = 0; n2 < 4; ++n2)
    bb0[n2] = *(const f16x8*)(bBase + (size_t)n2 * 512);
#pragma unroll
  for (int n2 = 0; n2 < 4; ++n2)
    bb1v[n2] = *(const f16x8*)(bBase + (size_t)(4 + n2) * 512);
  Rphase(0);
  __syncthreads();

#pragma unroll
  for (int kc = 0; kc < 8; ++kc) {
    const _Float16* buf = XF + ((kc & 1) * 8192);
#pragma unroll
    for (int j = 0; j < 4; ++j) {
      if (j == 2 && kc < 7) Rphase(kc + 1);
      int kt = kc * 4 + j;
      f16x8 xa[4];
#pragma unroll
      for (int mi = 0; mi < 4; ++mi)
        xa[mi] = *(const f16x8*)(buf + (size_t)(j * 4 + mi) * 512 + l * 8);
      // half 0 (ni 0..3)
#pragma unroll
      for (int mi = 0; mi < 4; ++mi)
#pragma unroll
        for (int n2 = 0; n2 < 4; ++n2)
          acc[mi][n2] = __builtin_amdgcn_mfma_f32_16x16x32_f16(bb0[n2], xa[mi], acc[mi][n2], 0, 0, 0);
      if (kt < 31) {
#pragma unroll
        for (int n2 = 0; n2 < 4; ++n2)
          bb0[n2] = *(const f16x8*)(bBase + (size_t)((kt + 1) * 64 + n2) * 512);
      }
      // half 1 (ni 4..7)
#pragma unroll
      for (int mi = 0; mi < 4; ++mi)
#pragma unroll
        for (int n2 = 0; n2 < 4; ++n2)
          acc[mi][4 + n2] = __builtin_amdgcn_mfma_f32_16x16x32_f16(bb1v[n2], xa[mi], acc[mi][4 + n2], 0, 0, 0);
      if (kt < 31) {
#pragma unroll
        for (int n2 = 0; n2 < 4; ++n2)
          bb1v[n2] = *(const f16x8*)(bBase + (size_t)((kt + 1) * 64 + 4 + n2) * 512);
      }
    }
    __syncthreads();
  }

  // epilogue: tanh+gate in registers -> direct fragment-major x2p stores
#pragma unroll
  for (int mi = 0; mi < 4; ++mi) {
    int rt = bm * 4 + mi;
#pragma unroll
    for (int p2 = 0; p2 < 4; ++p2) {
      int kc2 = (nt0 >> 1) + p2;
      float sg2 = sigmoid_fast(g2[kc2]);
      f32x4 c0 = *(const f32x4*)(b2 + kc2 * 32 + q * 4);
      f32x4 c1 = *(const f32x4*)(b2 + kc2 * 32 + 16 + q * 4);
      f16x8 o;
#pragma unroll
      for (int r = 0; r < 4; ++r) {
        o[r]     = (_Float16)(tanh_fast(acc[mi][2 * p2][r] + c0[r]) * sg2);
        o[4 + r] = (_Float16)(tanh_fast(acc[mi][2 * p2 + 1][r] + c1[r]) * sg2);
      }
      *(f16x8*)(x2p + ((size_t)kc2 * NRT + rt) * 512 + l * 8) = o;
    }
  }
}

// ---------------- K3: fused q-network head (unchanged) ----------------
__global__ __launch_bounds__(512, 3) void k3_head(
    const _Float16* __restrict__ x2p, const _Float16* __restrict__ t1p,
    const _Float16* __restrict__ t2p,
    const float* __restrict__ bq1, const float* __restrict__ ln1g, const float* __restrict__ ln1b,
    const float* __restrict__ bq2, const float* __restrict__ ln2g, const float* __restrict__ ln2b,
    const float* __restrict__ wq3, const float* __restrict__ bq3,
    float* __restrict__ out, int NRT, int SROWS) {
  __shared__ __align__(16) _Float16 y1h[128 * 264];
  __shared__ float redA[128 * 4], redB[128 * 4];
  __shared__ float meanv[128], rstdv[128];
  int bm = blockIdx.x;
  int t = threadIdx.x, w = t >> 6, l = t & 63, q = l >> 4, l15 = l & 15;
  int wr = w >> 2, wc = w & 3;

  int gt = bm * 8;
  int slice = 0;
  if (gt >= NRT) { slice = 1; gt -= NRT; }
  int rt0 = gt + wr * 4;

  f32x4 acc[4][4] = {};
  const size_t aStep = (size_t)NRT * 512;
  const _Float16* aP = x2p + (size_t)slice * SROWS * 1024 + (size_t)rt0 * 512 + (size_t)l * 8;
  const _Float16* bP = t1p + (size_t)(wc * 4) * 512 + (size_t)l * 8;

  f16x8 a0[4], a1[4], b0[4], b1[4];
#pragma unroll
  for (int mi = 0; mi < 4; ++mi) a0[mi] = *(const f16x8*)(aP + mi * 512);
#pragma unroll
  for (int ni = 0; ni < 4; ++ni) b0[ni] = *(const f16x8*)(bP + ni * 512);
#pragma unroll
  for (int mi = 0; mi < 4; ++mi) a1[mi] = *(const f16x8*)(aP + aStep + mi * 512);
#pragma unroll
  for (int ni = 0; ni < 4; ++ni) b1[ni] = *(const f16x8*)(bP + 8192 + ni * 512);
  aP += 2 * aStep; bP += 16384;

  for (int kt = 0; kt < 32; kt += 2) {
#pragma unroll
    for (int mi = 0; mi < 4; ++mi)
#pragma unroll
      for (int ni = 0; ni < 4; ++ni)
        acc[mi][ni] = __builtin_amdgcn_mfma_f32_16x16x32_f16(a0[mi], b0[ni], acc[mi][ni], 0, 0, 0);
    if (kt < 30) {
#pragma unroll
      for (int mi = 0; mi < 4; ++mi) a0[mi] = *(const f16x8*)(aP + mi * 512);
#pragma unroll
      for (int ni = 0; ni < 4; ++ni) b0[ni] = *(const f16x8*)(bP + ni * 512);
    }
#pragma unroll
    for (int mi = 0; mi < 4; ++mi)
#pragma unroll
      for (int ni = 0; ni < 4; ++ni)
        acc[mi][ni] = __builtin_amdgcn_mfma_f32_16x16x32_f16(a1[mi], b1[ni], acc[mi][ni], 0, 0, 0);
    if (kt < 30) {
#pragma unroll
      for (int mi = 0; mi < 4; ++mi) a1[mi] = *(const f16x8*)(aP + aStep + mi * 512);
#pragma unroll
      for (int ni = 0; ni < 4; ++ni) b1[ni] = *(const f16x8*)(bP + 8192 + ni * 512);
      aP += 2 * aStep; bP += 16384;
    }
  }

#pragma unroll
  for (int ni = 0; ni < 4; ++ni) {
    int col = wc * 64 + ni * 16 + l15;
    float b = bq1[col];
#pragma unroll
    for (int mi = 0; mi < 4; ++mi)
#pragma unroll
      for (int r = 0; r < 4; ++r) acc[mi][ni][r] += b;
  }
#pragma unroll
  for (int mi = 0; mi < 4; ++mi)
#pragma unroll
    for (int r = 0; r < 4; ++r) {
      int row = wr * 64 + mi * 16 + q * 4 + r;
      float s = 0.f, sq = 0.f;
#pragma unroll
      for (int ni = 0; ni < 4; ++ni) { float v = acc[mi][ni][r]; s += v; sq += v * v; }
#pragma unroll
      for (int off = 1; off < 16; off <<= 1) { s += __shfl_xor(s, off); sq += __shfl_xor(sq, off); }
      if (l15 == 0) { redA[row * 4 + wc] = s; redB[row * 4 + wc] = sq; }
    }
  __syncthreads();
  if (t < 128) {
    float s  = redA[t * 4] + redA[t * 4 + 1] + redA[t * 4 + 2] + redA[t * 4 + 3];
    float sq = redB[t * 4] + redB[t * 4 + 1] + redB[t * 4 + 2] + redB[t * 4 + 3];
    float mean = s * (1.0f / 256.0f);
    float var = sq * (1.0f / 256.0f) - mean * mean;
    meanv[t] = mean; rstdv[t] = rsqrtf(var + 1e-5f);
  }
  __syncthreads();
#pragma unroll
  for (int mi = 0; mi < 4; ++mi)
#pragma unroll
    for (int ni = 0; ni < 4; ++ni)
#pragma unroll
      for (int r = 0; r < 4; ++r) {
        int row = wr * 64 + mi * 16 + q * 4 + r;
        int col = wc * 64 + ni * 16 + l15;
        float y = (acc[mi][ni][r] - meanv[row]) * rstdv[row] * ln1g[col] + ln1b[col];
        y = fmaxf(y, 0.f);
        y1h[row * 264 + col] = (_Float16)y;
      }
  __syncthreads();

  f32x4 a2[4][2] = {};
  for (int kt = 0; kt < 8; ++kt) {
    f16x8 af2[4];
#pragma unroll
    for (int mi = 0; mi < 4; ++mi)
      af2[mi] = *(const f16x8*)&y1h[(wr * 64 + mi * 16 + l15) * 264 + kt * 32 + q * 8];
#pragma unroll
    for (int ni = 0; ni < 2; ++ni) {
      f16x8 bf = *(const f16x8*)(t2p + (size_t)(wc * 2 + ni) * 4096 + kt * 512 + l * 8);
#pragma unroll
      for (int mi = 0; mi < 4; ++mi)
        a2[mi][ni] = __builtin_amdgcn_mfma_f32_16x16x32_f16(af2[mi], bf, a2[mi][ni], 0, 0, 0);
    }
  }
#pragma unroll
  for (int ni = 0; ni < 2; ++ni) {
    int col = wc * 32 + ni * 16 + l15;
    float b = bq2[col];
#pragma unroll
    for (int mi = 0; mi < 4; ++mi)
#pragma unroll
      for (int r = 0; r < 4; ++r) a2[mi][ni][r] += b;
  }
  __syncthreads();
#pragma unroll
  for (int mi = 0; mi < 4; ++mi)
#pragma unroll
    for (int r = 0; r < 4; ++r) {
      int row = wr * 64 + mi * 16 + q * 4 + r;
      float s = 0.f, sq = 0.f;
#pragma unroll
      for (int ni = 0; ni < 2; ++ni) { float v = a2[mi][ni][r]; s += v; sq += v * v; }
#pragma unroll
      for (int off = 1; off < 16; off <<= 1) { s += __shfl_xor(s, off); sq += __shfl_xor(sq, off); }
      if (l15 == 0) { redA[row * 4 + wc] = s; redB[row * 4 + wc] = sq; }
    }
  __syncthreads();
  if (t < 128) {
    float s  = redA[t * 4] + redA[t * 4 + 1] + redA[t * 4 + 2] + redA[t * 4 + 3];
    float sq = redB[t * 4] + redB[t * 4 + 1] + redB[t * 4 + 2] + redB[t * 4 + 3];
    float mean = s * (1.0f / 128.0f);
    float var = sq * (1.0f / 128.0f) - mean * mean;
    meanv[t] = mean; rstdv[t] = rsqrtf(var + 1e-5f);
  }
  __syncthreads();
#pragma unroll
  for (int mi = 0; mi < 4; ++mi)
#pragma unroll
    for (int r = 0; r < 4; ++r) {
      int row = wr * 64 + mi * 16 + q * 4 + r;
      float pr = 0.f;
#pragma unroll
      for (int ni = 0; ni < 2; ++ni) {
        int col = wc * 32 + ni * 16 + l15;
        float y = (a2[mi][ni][r] - meanv[row]) * rstdv[row] * ln2g[col] + ln2b[col];
        y = fmaxf(y, 0.f);
        pr += y * wq3[col];
      }
#pragma unroll
      for (int off = 1; off < 16; off <<= 1) pr += __shfl_xor(pr, off);
      if (l15 == 0) redA[row * 4 + wc] = pr;
    }
  __syncthreads();
  if (t < 128)
    out[bm * 128 + t] = redA[t * 4] + redA[t * 4 + 1] + redA[t * 4 + 2] + redA[t * 4 + 3] + bq3[0];
}

// ---------------- launcher ----------------
extern "C" void kernel_launch(void* const* d_in, const int* in_sizes, int n_in,
                              void* d_out, int out_size, void* d_ws, size_t ws_size,
                              hipStream_t stream) {
  const float* state  = (const float*)d_in[0];
  const float* action = (const float*)d_in[1];
  const float* W1  = (const float*)d_in[2];
  const float* b1  = (const float*)d_in[3];
  const float* g1  = (const float*)d_in[4];
  const float* W2  = (const float*)d_in[5];
  const float* b2  = (const float*)d_in[6];
  const float* g2  = (const float*)d_in[7];
  const float* Wq1 = (const float*)d_in[8];
  const float* bq1 = (const float*)d_in[9];
  const float* ln1g = (const float*)d_in[10];
  const float* ln1b = (const float*)d_in[11];
  const float* Wq2 = (const float*)d_in[12];
  const float* bq2 = (const float*)d_in[13];
  const float* ln2g = (const float*)d_in[14];
  const float* ln2b = (const float*)d_in[15];
  const float* Wq3 = (const float*)d_in[16];
  const float* bq3 = (const float*)d_in[17];
  int B = in_sizes[0] / 24;

  char* ws = (char*)d_ws;
  _Float16* V1p = (_Float16*)(ws);
  _Float16* V2p = (_Float16*)(ws + 65536);
  _Float16* T1p = (_Float16*)(ws + 65536 + 2097152);
  _Float16* T2p = (_Float16*)(ws + 65536 + 2097152 + 524288);
  size_t woff = (65536 + 2097152 + 524288 + 65536 + 4095) & ~(size_t)4095;

  size_t avail = ws_size > woff ? ws_size - woff : 0;
  long rows = (long)(avail / 2048);     // x2 fp16 1024-wide
  if (rows > 32768) rows = 32768;
  rows &= ~127L;
  if (rows < 128) rows = 128;
  int S = (int)rows;
  _Float16* x2 = (_Float16*)(ws + woff);
  int NRT = S / 16;

  prep_weights<<<2656, 256, 0, stream>>>(W1, W2, Wq1, Wq2, V1p, V2p, T1p, T2p);

  for (int r0 = 0; r0 < B; r0 += S) {
    int Sc = S < (B - r0) ? S : (B - r0);
    int nbm = Sc / 128;
    k12_fused<<<dim3(2 * (Sc / 64)), 256, 0, stream>>>(state, action, V1p, b1, g1,
                                                       V2p, b2, g2, x2, r0, NRT);
    k3_head<<<dim3(nbm), 512, 0, stream>>>(x2, T1p, T2p, bq1, ln1g, ln1b,
                                           bq2, ln2g, ln2b, Wq3, bq3,
                                           (float*)d_out + r0, NRT, S);
  }
}

// Round 4
// 565.722 us; speedup vs baseline: 1.2279x; 1.1336x over previous
//
#include <hip/hip_runtime.h>
#include <hip/hip_bf16.h>

typedef _Float16 f16x8 __attribute__((ext_vector_type(8)));
typedef _Float16 f16x4 __attribute__((ext_vector_type(4)));
typedef float f32x4 __attribute__((ext_vector_type(4)));

__device__ __forceinline__ float tanh_fast(float x) {
  float e = __expf(2.0f * x);
  return 1.0f - 2.0f * __builtin_amdgcn_rcpf(e + 1.0f);
}
__device__ __forceinline__ float sigmoid_fast(float x) {
  return __builtin_amdgcn_rcpf(1.0f + __expf(-x));
}

// ---------------- K0: weight prep (unchanged) ----------------
// Fragment tiles of 512 hw. PI k-order (W2, Wq1): lane l elem j holds
// B[k = kt*32 + pi(q,j)][col = nt*16 + l15], pi(q,j) = q*4 + (j&3) + 16*(j>>2).
// Plain k-order (Wq2, W1): k = q*8 + j.
// V2p tile = kt*64 + nt; T1p tile = kt*16 + nt; T2p tile = nt*8 + kt.
__global__ __launch_bounds__(256) void prep_weights(
    const float* __restrict__ W1, const float* __restrict__ W2,
    const float* __restrict__ Wq1, const float* __restrict__ Wq2,
    _Float16* __restrict__ V1p, _Float16* __restrict__ V2p,
    _Float16* __restrict__ T1p, _Float16* __restrict__ T2p) {
  __shared__ float S[32 * 33];
  int b = blockIdx.x, t = threadIdx.x;
  if (b < 2624) {
    const float* in; _Float16* out; int N, nc0, tile, use_pi;
    if (b < 2048) {        // W2 [32][1024][32]: h, ntl, kt  (PI)
      int h = b >> 6, rem = b & 63, ntl = rem >> 5, kt = rem & 31;
      in = W2 + (size_t)h * 32768 + (size_t)kt * 32 * 32;
      N = 32; nc0 = ntl * 16;
      out = V2p; tile = kt * 64 + (h * 2 + ntl); use_pi = 1;
    } else if (b < 2560) { // Wq1 [1024][256]  (PI)
      int i = b - 2048, nt = i >> 5, kt = i & 31;
      in = Wq1 + (size_t)kt * 32 * 256; N = 256; nc0 = nt * 16;
      out = T1p; tile = kt * 16 + nt; use_pi = 1;
    } else {               // Wq2 [256][128]  (plain)
      int i = b - 2560, nt = i >> 3, kt = i & 7;
      in = Wq2 + (size_t)kt * 32 * 128; N = 128; nc0 = nt * 16;
      out = T2p; tile = nt * 8 + kt; use_pi = 0;
    }
    if (t < 128) {
      int r = t >> 2, c4 = (t & 3) * 4;
      const float4 v = *(const float4*)(in + (size_t)r * N + nc0 + c4);
      S[r * 17 + c4 + 0] = v.x; S[r * 17 + c4 + 1] = v.y;
      S[r * 17 + c4 + 2] = v.z; S[r * 17 + c4 + 3] = v.w;
    }
    __syncthreads();
    if (t < 128) {
      int w2 = t >> 6, l = t & 63, q = l >> 4, l15 = l & 15;
      f16x4 o;
#pragma unroll
      for (int jj = 0; jj < 4; ++jj) {
        int kl = use_pi ? (q * 4 + jj + w2 * 16) : (q * 8 + w2 * 4 + jj);
        o[jj] = (_Float16)S[kl * 17 + l15];
      }
      *(f16x4*)(out + (size_t)tile * 512 + l * 8 + w2 * 4) = o;
    }
  } else {                 // W1 [32][32][32]: one block per head h (plain)
    int h = b - 2624;
    const float* in = W1 + h * 1024;
    int cc = t & 31, rr8 = t >> 5;
#pragma unroll
    for (int p = 0; p < 4; ++p) {
      int r = rr8 + p * 8;
      S[cc * 33 + r] = in[r * 32 + cc];
    }
    __syncthreads();
    if (t < 128) {
      int ntl = t >> 6, l = t & 63, q = l >> 4, l15 = l & 15;
      f16x8 o;
#pragma unroll
      for (int j = 0; j < 8; ++j)
        o[j] = (_Float16)S[(ntl * 16 + l15) * 33 + q * 8 + j];
      *(f16x8*)(V1p + (size_t)(h * 2 + ntl) * 512 + l * 8) = o;
    }
  }
}

// ---------------- K12: fused ripple1+ripple2, 64x1024 blocks ----------------
// Block = 64 rows x FULL 1024 cols, 512 threads = 8 waves; wave = 64 rows x
// 128 cols (nt0 = w*8), acc[4][8] identical to verified kernel. Ripple1
// redundancy = 1x: block produces its own x1 tile once into a 2x64KB LDS
// dbuf (16 k-tiles per buffer) and consumes all 32 k-tiles. Only 3 barriers
// per block (SA stage, after produce-ph0, phase boundary); ph1 production
// (heads 16..31) is interleaved into ph0 consumption at ktl==6/10, writing
// buf1 while buf0 is read. A-fragments ping-pong in registers (xab[2][4],
// full unroll -> static indexing). LDS 136 KB -> 1 block/CU, 2 waves/SIMD
// (256 combined VGPR+AGPR regs is the hard occupancy cap anyway).
__global__ __launch_bounds__(512, 2) void k12_fused(
    const float* __restrict__ state, const float* __restrict__ action,
    const _Float16* __restrict__ v1p, const float* __restrict__ b1,
    const float* __restrict__ g1,
    const _Float16* __restrict__ v2p, const float* __restrict__ b2,
    const float* __restrict__ g2,
    _Float16* __restrict__ x2p, int gro, int NRT) {
  __shared__ __align__(16) _Float16 SA[64 * 40];          // 5 KB
  __shared__ __align__(16) _Float16 XB[2][16 * 4 * 512];  // 2 x 64 KB
  int bm = blockIdx.x;
  int t = threadIdx.x, w = t >> 6, l = t & 63, q = l >> 4, l15 = l & 15;
  int m0 = bm * 64;

  {  // stage sa tile [64][32] fp16, stride 40; 8 threads/row (4 floats each)
    int r = t >> 3, qq = t & 7;
    size_t grow = (size_t)(gro + m0 + r);
    const float* src = (qq < 6) ? (state + grow * 24 + qq * 4)
                                : (action + grow * 8 + (qq - 6) * 4);
    float4 v = *(const float4*)src;
    f16x4 h;
    h[0] = (_Float16)v.x; h[1] = (_Float16)v.y;
    h[2] = (_Float16)v.z; h[3] = (_Float16)v.w;
    *(f16x4*)&SA[r * 40 + qq * 4] = h;
  }
  __syncthreads();

  // loop-invariant sa fragments (B operand of producer MFMAs), 64 rows
  f16x8 asa[4];
#pragma unroll
  for (int p = 0; p < 4; ++p)
    asa[p] = *(const f16x8*)&SA[(p * 16 + l15) * 40 + q * 8];

  const int nt0 = w * 8;
  const _Float16* bBase = v2p + (size_t)nt0 * 512 + (size_t)l * 8;
  f32x4 acc[4][8] = {};

  // produce head h (x1 cols h*32..h*32+31) for the block's 64 rows into
  // XB[buf] tiles (h&15)*4 + p. Content layout identical to verified kernel.
  auto produce = [&](int h, int buf) {
    f16x8 rb0 = *(const f16x8*)(v1p + (size_t)(2 * h) * 512 + l * 8);
    f16x8 rb1 = *(const f16x8*)(v1p + (size_t)(2 * h + 1) * 512 + l * 8);
    float sg = sigmoid_fast(g1[h]);
    f32x4 bs0 = *(const f32x4*)(b1 + h * 32 + q * 4);
    f32x4 bs1 = *(const f32x4*)(b1 + h * 32 + 16 + q * 4);
    _Float16* bw = &XB[buf][(size_t)((h & 15) * 4) * 512 + l * 8];
#pragma unroll
    for (int p = 0; p < 4; ++p) {
      f32x4 d0 = {}, d1 = {};
      d0 = __builtin_amdgcn_mfma_f32_16x16x32_f16(rb0, asa[p], d0, 0, 0, 0);
      d1 = __builtin_amdgcn_mfma_f32_16x16x32_f16(rb1, asa[p], d1, 0, 0, 0);
      f16x8 o;
#pragma unroll
      for (int r = 0; r < 4; ++r) {
        o[r]     = (_Float16)(tanh_fast(d0[r] + bs0[r]) * sg);
        o[4 + r] = (_Float16)(tanh_fast(d1[r] + bs1[r]) * sg);
      }
      *(f16x8*)(bw + (size_t)p * 512) = o;
    }
  };

  // prologue: B stream kt=0 (latency hidden under produce) + produce ph0
  f16x8 bb0[4], bb1v[4];
#pragma unroll
  for (int n2 = 0; n2 < 4; ++n2)
    bb0[n2] = *(const f16x8*)(bBase + (size_t)n2 * 512);
#pragma unroll
  for (int n2 = 0; n2 < 4; ++n2)
    bb1v[n2] = *(const f16x8*)(bBase + (size_t)(4 + n2) * 512);
  produce(w * 2, 0);
  produce(w * 2 + 1, 0);
  __syncthreads();

  f16x8 xab[2][4];
#pragma unroll
  for (int mi = 0; mi < 4; ++mi)
    xab[0][mi] = *(const f16x8*)&XB[0][(size_t)mi * 512 + l * 8];

  // phase 0: kt 0..15 from XB[0]; interleave production of heads 16..31
#pragma unroll
  for (int ktl = 0; ktl < 16; ++ktl) {
    int kt = ktl;
    if (ktl == 6)  produce(16 + w * 2, 1);
    if (ktl == 10) produce(16 + w * 2 + 1, 1);
    if (ktl < 15) {
#pragma unroll
      for (int mi = 0; mi < 4; ++mi)
        xab[(ktl + 1) & 1][mi] =
            *(const f16x8*)&XB[0][(size_t)((ktl + 1) * 4 + mi) * 512 + l * 8];
    }
    // half 0 (ni 0..3)
#pragma unroll
    for (int mi = 0; mi < 4; ++mi)
#pragma unroll
      for (int n2 = 0; n2 < 4; ++n2)
        acc[mi][n2] = __builtin_amdgcn_mfma_f32_16x16x32_f16(
            bb0[n2], xab[ktl & 1][mi], acc[mi][n2], 0, 0, 0);
#pragma unroll
    for (int n2 = 0; n2 < 4; ++n2)
      bb0[n2] = *(const f16x8*)(bBase + (size_t)((kt + 1) * 64 + n2) * 512);
    // half 1 (ni 4..7)
#pragma unroll
    for (int mi = 0; mi < 4; ++mi)
#pragma unroll
      for (int n2 = 0; n2 < 4; ++n2)
        acc[mi][4 + n2] = __builtin_amdgcn_mfma_f32_16x16x32_f16(
            bb1v[n2], xab[ktl & 1][mi], acc[mi][4 + n2], 0, 0, 0);
#pragma unroll
    for (int n2 = 0; n2 < 4; ++n2)
      bb1v[n2] = *(const f16x8*)(bBase + (size_t)((kt + 1) * 64 + 4 + n2) * 512);
  }
  __syncthreads();

#pragma unroll
  for (int mi = 0; mi < 4; ++mi)
    xab[0][mi] = *(const f16x8*)&XB[1][(size_t)mi * 512 + l * 8];

  // phase 1: kt 16..31 from XB[1]
#pragma unroll
  for (int ktl = 0; ktl < 16; ++ktl) {
    int kt = 16 + ktl;
    if (ktl < 15) {
#pragma unroll
      for (int mi = 0; mi < 4; ++mi)
        xab[(ktl + 1) & 1][mi] =
            *(const f16x8*)&XB[1][(size_t)((ktl + 1) * 4 + mi) * 512 + l * 8];
    }
    // half 0 (ni 0..3)
#pragma unroll
    for (int mi = 0; mi < 4; ++mi)
#pragma unroll
      for (int n2 = 0; n2 < 4; ++n2)
        acc[mi][n2] = __builtin_amdgcn_mfma_f32_16x16x32_f16(
            bb0[n2], xab[ktl & 1][mi], acc[mi][n2], 0, 0, 0);
    if (kt < 31) {
#pragma unroll
      for (int n2 = 0; n2 < 4; ++n2)
        bb0[n2] = *(const f16x8*)(bBase + (size_t)((kt + 1) * 64 + n2) * 512);
    }
    // half 1 (ni 4..7)
#pragma unroll
    for (int mi = 0; mi < 4; ++mi)
#pragma unroll
      for (int n2 = 0; n2 < 4; ++n2)
        acc[mi][4 + n2] = __builtin_amdgcn_mfma_f32_16x16x32_f16(
            bb1v[n2], xab[ktl & 1][mi], acc[mi][4 + n2], 0, 0, 0);
    if (kt < 31) {
#pragma unroll
      for (int n2 = 0; n2 < 4; ++n2)
        bb1v[n2] = *(const f16x8*)(bBase + (size_t)((kt + 1) * 64 + 4 + n2) * 512);
    }
  }

  // epilogue: tanh+gate in registers -> direct fragment-major x2p stores
#pragma unroll
  for (int mi = 0; mi < 4; ++mi) {
    int rt = bm * 4 + mi;
#pragma unroll
    for (int p2 = 0; p2 < 4; ++p2) {
      int kc2 = (nt0 >> 1) + p2;
      float sg2 = sigmoid_fast(g2[kc2]);
      f32x4 c0 = *(const f32x4*)(b2 + kc2 * 32 + q * 4);
      f32x4 c1 = *(const f32x4*)(b2 + kc2 * 32 + 16 + q * 4);
      f16x8 o;
#pragma unroll
      for (int r = 0; r < 4; ++r) {
        o[r]     = (_Float16)(tanh_fast(acc[mi][2 * p2][r] + c0[r]) * sg2);
        o[4 + r] = (_Float16)(tanh_fast(acc[mi][2 * p2 + 1][r] + c1[r]) * sg2);
      }
      *(f16x8*)(x2p + ((size_t)kc2 * NRT + rt) * 512 + l * 8) = o;
    }
  }
}

// ---------------- K3: fused q-network head (unchanged) ----------------
__global__ __launch_bounds__(512, 3) void k3_head(
    const _Float16* __restrict__ x2p, const _Float16* __restrict__ t1p,
    const _Float16* __restrict__ t2p,
    const float* __restrict__ bq1, const float* __restrict__ ln1g, const float* __restrict__ ln1b,
    const float* __restrict__ bq2, const float* __restrict__ ln2g, const float* __restrict__ ln2b,
    const float* __restrict__ wq3, const float* __restrict__ bq3,
    float* __restrict__ out, int NRT, int SROWS) {
  __shared__ __align__(16) _Float16 y1h[128 * 264];
  __shared__ float redA[128 * 4], redB[128 * 4];
  __shared__ float meanv[128], rstdv[128];
  int bm = blockIdx.x;
  int t = threadIdx.x, w = t >> 6, l = t & 63, q = l >> 4, l15 = l & 15;
  int wr = w >> 2, wc = w & 3;

  int gt = bm * 8;
  int slice = 0;
  if (gt >= NRT) { slice = 1; gt -= NRT; }
  int rt0 = gt + wr * 4;

  f32x4 acc[4][4] = {};
  const size_t aStep = (size_t)NRT * 512;
  const _Float16* aP = x2p + (size_t)slice * SROWS * 1024 + (size_t)rt0 * 512 + (size_t)l * 8;
  const _Float16* bP = t1p + (size_t)(wc * 4) * 512 + (size_t)l * 8;

  f16x8 a0[4], a1[4], b0[4], b1[4];
#pragma unroll
  for (int mi = 0; mi < 4; ++mi) a0[mi] = *(const f16x8*)(aP + mi * 512);
#pragma unroll
  for (int ni = 0; ni < 4; ++ni) b0[ni] = *(const f16x8*)(bP + ni * 512);
#pragma unroll
  for (int mi = 0; mi < 4; ++mi) a1[mi] = *(const f16x8*)(aP + aStep + mi * 512);
#pragma unroll
  for (int ni = 0; ni < 4; ++ni) b1[ni] = *(const f16x8*)(bP + 8192 + ni * 512);
  aP += 2 * aStep; bP += 16384;

  for (int kt = 0; kt < 32; kt += 2) {
#pragma unroll
    for (int mi = 0; mi < 4; ++mi)
#pragma unroll
      for (int ni = 0; ni < 4; ++ni)
        acc[mi][ni] = __builtin_amdgcn_mfma_f32_16x16x32_f16(a0[mi], b0[ni], acc[mi][ni], 0, 0, 0);
    if (kt < 30) {
#pragma unroll
      for (int mi = 0; mi < 4; ++mi) a0[mi] = *(const f16x8*)(aP + mi * 512);
#pragma unroll
      for (int ni = 0; ni < 4; ++ni) b0[ni] = *(const f16x8*)(bP + ni * 512);
    }
#pragma unroll
    for (int mi = 0; mi < 4; ++mi)
#pragma unroll
      for (int ni = 0; ni < 4; ++ni)
        acc[mi][ni] = __builtin_amdgcn_mfma_f32_16x16x32_f16(a1[mi], b1[ni], acc[mi][ni], 0, 0, 0);
    if (kt < 30) {
#pragma unroll
      for (int mi = 0; mi < 4; ++mi) a1[mi] = *(const f16x8*)(aP + aStep + mi * 512);
#pragma unroll
      for (int ni = 0; ni < 4; ++ni) b1[ni] = *(const f16x8*)(bP + 8192 + ni * 512);
      aP += 2 * aStep; bP += 16384;
    }
  }

#pragma unroll
  for (int ni = 0; ni < 4; ++ni) {
    int col = wc * 64 + ni * 16 + l15;
    float b = bq1[col];
#pragma unroll
    for (int mi = 0; mi < 4; ++mi)
#pragma unroll
      for (int r = 0; r < 4; ++r) acc[mi][ni][r] += b;
  }
#pragma unroll
  for (int mi = 0; mi < 4; ++mi)
#pragma unroll
    for (int r = 0; r < 4; ++r) {
      int row = wr * 64 + mi * 16 + q * 4 + r;
      float s = 0.f, sq = 0.f;
#pragma unroll
      for (int ni = 0; ni < 4; ++ni) { float v = acc[mi][ni][r]; s += v; sq += v * v; }
#pragma unroll
      for (int off = 1; off < 16; off <<= 1) { s += __shfl_xor(s, off); sq += __shfl_xor(sq, off); }
      if (l15 == 0) { redA[row * 4 + wc] = s; redB[row * 4 + wc] = sq; }
    }
  __syncthreads();
  if (t < 128) {
    float s  = redA[t * 4] + redA[t * 4 + 1] + redA[t * 4 + 2] + redA[t * 4 + 3];
    float sq = redB[t * 4] + redB[t * 4 + 1] + redB[t * 4 + 2] + redB[t * 4 + 3];
    float mean = s * (1.0f / 256.0f);
    float var = sq * (1.0f / 256.0f) - mean * mean;
    meanv[t] = mean; rstdv[t] = rsqrtf(var + 1e-5f);
  }
  __syncthreads();
#pragma unroll
  for (int mi = 0; mi < 4; ++mi)
#pragma unroll
    for (int ni = 0; ni < 4; ++ni)
#pragma unroll
      for (int r = 0; r < 4; ++r) {
        int row = wr * 64 + mi * 16 + q * 4 + r;
        int col = wc * 64 + ni * 16 + l15;
        float y = (acc[mi][ni][r] - meanv[row]) * rstdv[row] * ln1g[col] + ln1b[col];
        y = fmaxf(y, 0.f);
        y1h[row * 264 + col] = (_Float16)y;
      }
  __syncthreads();

  f32x4 a2[4][2] = {};
  for (int kt = 0; kt < 8; ++kt) {
    f16x8 af2[4];
#pragma unroll
    for (int mi = 0; mi < 4; ++mi)
      af2[mi] = *(const f16x8*)&y1h[(wr * 64 + mi * 16 + l15) * 264 + kt * 32 + q * 8];
#pragma unroll
    for (int ni = 0; ni < 2; ++ni) {
      f16x8 bf = *(const f16x8*)(t2p + (size_t)(wc * 2 + ni) * 4096 + kt * 512 + l * 8);
#pragma unroll
      for (int mi = 0; mi < 4; ++mi)
        a2[mi][ni] = __builtin_amdgcn_mfma_f32_16x16x32_f16(af2[mi], bf, a2[mi][ni], 0, 0, 0);
    }
  }
#pragma unroll
  for (int ni = 0; ni < 2; ++ni) {
    int col = wc * 32 + ni * 16 + l15;
    float b = bq2[col];
#pragma unroll
    for (int mi = 0; mi < 4; ++mi)
#pragma unroll
      for (int r = 0; r < 4; ++r) a2[mi][ni][r] += b;
  }
  __syncthreads();
#pragma unroll
  for (int mi = 0; mi < 4; ++mi)
#pragma unroll
    for (int r = 0; r < 4; ++r) {
      int row = wr * 64 + mi * 16 + q * 4 + r;
      float s = 0.f, sq = 0.f;
#pragma unroll
      for (int ni = 0; ni < 2; ++ni) { float v = a2[mi][ni][r]; s += v; sq += v * v; }
#pragma unroll
      for (int off = 1; off < 16; off <<= 1) { s += __shfl_xor(s, off); sq += __shfl_xor(sq, off); }
      if (l15 == 0) { redA[row * 4 + wc] = s; redB[row * 4 + wc] = sq; }
    }
  __syncthreads();
  if (t < 128) {
    float s  = redA[t * 4] + redA[t * 4 + 1] + redA[t * 4 + 2] + redA[t * 4 + 3];
    float sq = redB[t * 4] + redB[t * 4 + 1] + redB[t * 4 + 2] + redB[t * 4 + 3];
    float mean = s * (1.0f / 128.0f);
    float var = sq * (1.0f / 128.0f) - mean * mean;
    meanv[t] = mean; rstdv[t] = rsqrtf(var + 1e-5f);
  }
  __syncthreads();
#pragma unroll
  for (int mi = 0; mi < 4; ++mi)
#pragma unroll
    for (int r = 0; r < 4; ++r) {
      int row = wr * 64 + mi * 16 + q * 4 + r;
      float pr = 0.f;
#pragma unroll
      for (int ni = 0; ni < 2; ++ni) {
        int col = wc * 32 + ni * 16 + l15;
        float y = (a2[mi][ni][r] - meanv[row]) * rstdv[row] * ln2g[col] + ln2b[col];
        y = fmaxf(y, 0.f);
        pr += y * wq3[col];
      }
#pragma unroll
      for (int off = 1; off < 16; off <<= 1) pr += __shfl_xor(pr, off);
      if (l15 == 0) redA[row * 4 + wc] = pr;
    }
  __syncthreads();
  if (t < 128)
    out[bm * 128 + t] = redA[t * 4] + redA[t * 4 + 1] + redA[t * 4 + 2] + redA[t * 4 + 3] + bq3[0];
}

// ---------------- launcher ----------------
extern "C" void kernel_launch(void* const* d_in, const int* in_sizes, int n_in,
                              void* d_out, int out_size, void* d_ws, size_t ws_size,
                              hipStream_t stream) {
  const float* state  = (const float*)d_in[0];
  const float* action = (const float*)d_in[1];
  const float* W1  = (const float*)d_in[2];
  const float* b1  = (const float*)d_in[3];
  const float* g1  = (const float*)d_in[4];
  const float* W2  = (const float*)d_in[5];
  const float* b2  = (const float*)d_in[6];
  const float* g2  = (const float*)d_in[7];
  const float* Wq1 = (const float*)d_in[8];
  const float* bq1 = (const float*)d_in[9];
  const float* ln1g = (const float*)d_in[10];
  const float* ln1b = (const float*)d_in[11];
  const float* Wq2 = (const float*)d_in[12];
  const float* bq2 = (const float*)d_in[13];
  const float* ln2g = (const float*)d_in[14];
  const float* ln2b = (const float*)d_in[15];
  const float* Wq3 = (const float*)d_in[16];
  const float* bq3 = (const float*)d_in[17];
  int B = in_sizes[0] / 24;

  char* ws = (char*)d_ws;
  _Float16* V1p = (_Float16*)(ws);
  _Float16* V2p = (_Float16*)(ws + 65536);
  _Float16* T1p = (_Float16*)(ws + 65536 + 2097152);
  _Float16* T2p = (_Float16*)(ws + 65536 + 2097152 + 524288);
  size_t woff = (65536 + 2097152 + 524288 + 65536 + 4095) & ~(size_t)4095;

  size_t avail = ws_size > woff ? ws_size - woff : 0;
  long rows = (long)(avail / 2048);     // x2 fp16 1024-wide
  if (rows > 32768) rows = 32768;
  rows &= ~127L;
  if (rows < 128) rows = 128;
  int S = (int)rows;
  _Float16* x2 = (_Float16*)(ws + woff);
  int NRT = S / 16;

  prep_weights<<<2656, 256, 0, stream>>>(W1, W2, Wq1, Wq2, V1p, V2p, T1p, T2p);

  for (int r0 = 0; r0 < B; r0 += S) {
    int Sc = S < (B - r0) ? S : (B - r0);
    int nbm = Sc / 128;
    k12_fused<<<dim3(Sc / 64), 512, 0, stream>>>(state, action, V1p, b1, g1,
                                                 V2p, b2, g2, x2, r0, NRT);
    k3_head<<<dim3(nbm), 512, 0, stream>>>(x2, T1p, T2p, bq1, ln1g, ln1b,
                                           bq2, ln2g, ln2b, Wq3, bq3,
                                           (float*)d_out + r0, NRT, S);
  }
}